// Round 1
// baseline (1772.036 us; speedup 1.0000x reference)
//
#include <hip/hip_runtime.h>
#include <hip/hip_bf16.h>

// Two-layer RGCN (mean aggregation per relation) for MI355X.
// Strategy: aggregate-then-transform.
//   agg[r][n][:] = sum over edges (s->n, rel r) of feat[s][:]
//   out[n][:]    = sum_r inv_cnt[r][n] * agg[r][n] @ W[r] + feat[n] @ root + bias
// inv_cnt computed once (same edge set both layers).

#define D_IN 128
#define NREL 8

// ---------------- degree count ----------------
__global__ void count_edges_kernel(const int* __restrict__ dst,
                                   const int* __restrict__ et,
                                   float* __restrict__ cnt, int E, int N) {
    int e = blockIdx.x * blockDim.x + threadIdx.x;
    if (e < E) atomicAdd(&cnt[(size_t)et[e] * N + dst[e]], 1.0f);
}

__global__ void inv_cnt_kernel(float* __restrict__ cnt, int n) {
    int i = blockIdx.x * blockDim.x + threadIdx.x;
    if (i < n) cnt[i] = 1.0f / fmaxf(cnt[i], 1.0f);
}

// ---------------- edge scatter: one wave (64 lanes) per edge ----------------
__global__ void scatter_kernel(const float* __restrict__ feat,
                               const int* __restrict__ src,
                               const int* __restrict__ dst,
                               const int* __restrict__ et,
                               float* __restrict__ agg, int E, int N) {
    int gid = blockIdx.x * blockDim.x + threadIdx.x;
    int e = gid >> 6;
    int lane = gid & 63;
    if (e >= E) return;
    int s = src[e], d = dst[e], t = et[e];
    float2 v = ((const float2*)(feat + (size_t)s * D_IN))[lane];
    float* p = agg + ((size_t)t * N + d) * D_IN + lane * 2;
    atomicAdd(p, v.x);
    atomicAdd(p + 1, v.y);
}

// ---------------- fused RGCN GEMM ----------------
// out[n][j] = bias[j] + Ain[n]@root[:,j] + sum_r inv_cnt[r][n] * agg[r][n] @ W[r][:,j]
// K-loop over 9 segments (8 relations + root), each K=128.
// block = 256 threads, BM = 64 rows, thread computes TM=4 rows x TN=NCOLS/16 cols.
template <int NCOLS, bool RELU>
__global__ __launch_bounds__(256) void rgcn_gemm_kernel(
    const float* __restrict__ Ain,   // [N][128] (x or h)
    const float* __restrict__ agg,   // [R][N][128]
    const float* __restrict__ invc,  // [R][N]
    const float* __restrict__ W,     // [R][128][NCOLS]
    const float* __restrict__ root,  // [128][NCOLS]
    const float* __restrict__ bias,  // [NCOLS]
    float* __restrict__ out,         // [N][NCOLS]
    int N) {
    constexpr int TM = 4;
    constexpr int TN = NCOLS / 16;  // 8 (NCOLS=128) or 4 (NCOLS=64)
    constexpr int BM = 64;
    constexpr int KT = 32;

    __shared__ float As[BM][KT + 4];
    __shared__ float Bs[KT][NCOLS + 4];
    __shared__ float sscale[BM];

    const int tid = threadIdx.x;
    const int cg = tid & 15;   // col group
    const int ng = tid >> 4;   // row group (0..15)
    const int nb = blockIdx.x * BM;

    float acc[TM][TN];
#pragma unroll
    for (int i = 0; i < TM; ++i)
#pragma unroll
        for (int u = 0; u < TN; ++u) acc[i][u] = 0.0f;

    for (int s = 0; s < NREL + 1; ++s) {
        const float* Aseg = (s < NREL) ? (agg + (size_t)s * N * D_IN) : Ain;
        const float* Bseg = (s < NREL) ? (W + (size_t)s * D_IN * NCOLS) : root;
        if (tid < BM) {
            int n = nb + tid;
            if (n >= N) n = N - 1;
            sscale[tid] = (s < NREL) ? invc[(size_t)s * N + n] : 1.0f;
        }
#pragma unroll
        for (int kt = 0; kt < D_IN; kt += KT) {
            __syncthreads();  // tiles free to overwrite; sscale visible
            // load A tile (scaled): BM x KT floats
#pragma unroll
            for (int it = 0; it < (BM * KT) / (4 * 256); ++it) {
                int idx = tid + it * 256;
                int row = idx >> 3;
                int c4 = (idx & 7) * 4;
                int n = nb + row;
                if (n >= N) n = N - 1;
                float4 v = *(const float4*)(Aseg + (size_t)n * D_IN + kt + c4);
                float sc = sscale[row];
                float4 w = make_float4(v.x * sc, v.y * sc, v.z * sc, v.w * sc);
                *(float4*)&As[row][c4] = w;
            }
            // load B tile: KT x NCOLS floats
#pragma unroll
            for (int it = 0; it < (KT * NCOLS) / (4 * 256); ++it) {
                int idx = tid + it * 256;
                int row = idx / (NCOLS / 4);
                int c4 = (idx % (NCOLS / 4)) * 4;
                float4 v = *(const float4*)(Bseg + (size_t)(kt + row) * NCOLS + c4);
                *(float4*)&Bs[row][c4] = v;
            }
            __syncthreads();
#pragma unroll
            for (int kk = 0; kk < KT; ++kk) {
                float a[TM];
#pragma unroll
                for (int i = 0; i < TM; ++i) a[i] = As[ng * TM + i][kk];
                float b[TN];
                *(float4*)&b[0] = *(const float4*)&Bs[kk][cg * TN];
                if (TN == 8) *(float4*)&b[4] = *(const float4*)&Bs[kk][cg * TN + 4];
#pragma unroll
                for (int i = 0; i < TM; ++i)
#pragma unroll
                    for (int u = 0; u < TN; ++u) acc[i][u] += a[i] * b[u];
            }
        }
    }

    // epilogue
    float bv[TN];
#pragma unroll
    for (int u = 0; u < TN; ++u) bv[u] = bias[cg * TN + u];
#pragma unroll
    for (int i = 0; i < TM; ++i) {
        int n = nb + ng * TM + i;
        if (n < N) {
            float o[TN];
#pragma unroll
            for (int u = 0; u < TN; ++u) {
                float v = acc[i][u] + bv[u];
                if (RELU) v = fmaxf(v, 0.0f);
                o[u] = v;
            }
            float* op = out + (size_t)n * NCOLS + cg * TN;
            *(float4*)&op[0] = *(const float4*)&o[0];
            if (TN == 8) *(float4*)&op[4] = *(const float4*)&o[4];
        }
    }
}

extern "C" void kernel_launch(void* const* d_in, const int* in_sizes, int n_in,
                              void* d_out, int out_size, void* d_ws, size_t ws_size,
                              hipStream_t stream) {
    const float* x = (const float*)d_in[0];
    const int* ei = (const int*)d_in[1];
    const int* et = (const int*)d_in[2];
    const float* W1 = (const float*)d_in[3];
    const float* root1 = (const float*)d_in[4];
    const float* bias1 = (const float*)d_in[5];
    const float* W2 = (const float*)d_in[6];
    const float* root2 = (const float*)d_in[7];
    const float* bias2 = (const float*)d_in[8];
    float* out = (float*)d_out;

    const int N = in_sizes[0] / D_IN;   // 50000
    const int E = in_sizes[2];          // 800000
    const int* src = ei;
    const int* dst = ei + E;

    // workspace layout
    float* agg = (float*)d_ws;                        // R*N*128 f32 = 204.8 MB
    float* invc = agg + (size_t)NREL * N * D_IN;      // R*N f32    = 1.6 MB
    float* h = invc + (size_t)NREL * N;               // N*128 f32  = 25.6 MB

    const size_t aggBytes = (size_t)NREL * N * D_IN * sizeof(float);

    // degree counts (shared by both layers)
    hipMemsetAsync(invc, 0, (size_t)NREL * N * sizeof(float), stream);
    count_edges_kernel<<<(E + 255) / 256, 256, 0, stream>>>(dst, et, invc, E, N);
    inv_cnt_kernel<<<(NREL * N + 255) / 256, 256, 0, stream>>>(invc, NREL * N);

    const int scatterBlocks = (int)(((size_t)E * 64 + 255) / 256);
    const int gemmBlocks = (N + 63) / 64;

    // ---- layer 1 ----
    hipMemsetAsync(agg, 0, aggBytes, stream);
    scatter_kernel<<<scatterBlocks, 256, 0, stream>>>(x, src, dst, et, agg, E, N);
    rgcn_gemm_kernel<128, true><<<gemmBlocks, 256, 0, stream>>>(
        x, agg, invc, W1, root1, bias1, h, N);

    // ---- layer 2 ----
    hipMemsetAsync(agg, 0, aggBytes, stream);
    scatter_kernel<<<scatterBlocks, 256, 0, stream>>>(h, src, dst, et, agg, E, N);
    rgcn_gemm_kernel<64, false><<<gemmBlocks, 256, 0, stream>>>(
        h, agg, invc, W2, root2, bias2, out, N);
}

// Round 5
// 375.619 us; speedup vs baseline: 4.7176x; 4.7176x over previous
//
#include <hip/hip_runtime.h>
#include <hip/hip_bf16.h>

// Two-layer RGCN (mean aggregation per relation) for MI355X.
// Round 5: CSR atomic-free aggregation (round-2 plan, still unmeasured due to
// infra) + bf16 feature path + MFMA 16x16x32_bf16 fused GEMM.
//   agg[s][:] = mean over edges in segment s of feat[src]   (bf16, 0 if empty)
//   out[n][:] = sum_r agg[r*N+n] @ W[r] + feat[n] @ root + bias
// A/B MFMA fragments use a consistent k-permutation (kappa(g,j)=8g+j for BOTH
// operands) -> result independent of HW internal k-order. C/D layout is the
// HW-verified col=lane&15, row=(lane>>4)*4+reg.

#define D_IN 128
#define NREL 8

typedef short bf16x8 __attribute__((ext_vector_type(8)));
typedef float f32x4 __attribute__((ext_vector_type(4)));

__device__ __forceinline__ ushort cvbf(float f) {  // f32 -> bf16 RNE
    unsigned u = __float_as_uint(f);
    return (ushort)((u + 0x7FFFu + ((u >> 16) & 1u)) >> 16);
}
__device__ __forceinline__ float bflo(unsigned v) { return __uint_as_float(v << 16); }
__device__ __forceinline__ float bfhi(unsigned v) { return __uint_as_float(v & 0xFFFF0000u); }

// ---------------- f32 -> bf16 convert (4 elems/thread) ----------------
__global__ void to_bf16_kernel(const float* __restrict__ in,
                               ushort* __restrict__ out, int n4) {
    int i = blockIdx.x * blockDim.x + threadIdx.x;
    if (i >= n4) return;
    float4 v = ((const float4*)in)[i];
    ushort4 o;
    o.x = cvbf(v.x); o.y = cvbf(v.y); o.z = cvbf(v.z); o.w = cvbf(v.w);
    ((ushort4*)out)[i] = o;
}

// ---------------- weight pre-transform: bf16, transposed, XOR-swizzled ------
// Wt[s][n][k'] where byte-in-row = (k*2) ^ ((n&7)<<4). Segment s<NREL from W,
// s==NREL from root.
__global__ void wt_transform_kernel(const float* __restrict__ W,
                                    const float* __restrict__ root,
                                    ushort* __restrict__ Wt, int NCOLS) {
    int i = blockIdx.x * blockDim.x + threadIdx.x;
    int tot = (NREL + 1) * D_IN * NCOLS;
    if (i >= tot) return;
    int s = i / (D_IN * NCOLS);
    int r = i - s * D_IN * NCOLS;
    int k = r / NCOLS;
    int n = r - k * NCOLS;
    float v = (s < NREL) ? W[(size_t)s * D_IN * NCOLS + (size_t)k * NCOLS + n]
                         : root[(size_t)k * NCOLS + n];
    int byteoff = (k << 1) ^ ((n & 7) << 4);
    Wt[(size_t)s * NCOLS * D_IN + (size_t)n * D_IN + (byteoff >> 1)] = cvbf(v);
}

// ---------------- CSR build ----------------
__global__ void count_kernel(const int* __restrict__ dst,
                             const int* __restrict__ et,
                             int* __restrict__ cnt, int E, int N) {
    int e = blockIdx.x * blockDim.x + threadIdx.x;
    if (e < E) atomicAdd(&cnt[et[e] * N + dst[e]], 1);
}

__global__ void scan_block_sum(const int* __restrict__ cnt,
                               int* __restrict__ bsum, int nseg) {
    __shared__ int s[256];
    int base = blockIdx.x * 1024 + threadIdx.x * 4;
    int v = 0;
#pragma unroll
    for (int i = 0; i < 4; ++i) {
        int idx = base + i;
        if (idx < nseg) v += cnt[idx];
    }
    s[threadIdx.x] = v;
    __syncthreads();
    for (int off = 128; off > 0; off >>= 1) {
        if (threadIdx.x < off) s[threadIdx.x] += s[threadIdx.x + off];
        __syncthreads();
    }
    if (threadIdx.x == 0) bsum[blockIdx.x] = s[0];
}

__global__ void scan_bsum(int* __restrict__ bsum, int nb) {
    __shared__ int s[512];
    int t = threadIdx.x;
    int my = (t < nb) ? bsum[t] : 0;
    s[t] = my;
    __syncthreads();
    for (int off = 1; off < 512; off <<= 1) {
        int v = (t >= off) ? s[t - off] : 0;
        __syncthreads();
        s[t] += v;
        __syncthreads();
    }
    if (t < nb) bsum[t] = s[t] - my;  // exclusive
}

__global__ void scan_write(const int* __restrict__ cnt,
                           const int* __restrict__ bsum,
                           int* __restrict__ off, int nseg) {
    __shared__ int s[256];
    int t = threadIdx.x;
    int base = blockIdx.x * 1024 + t * 4;
    int v[4];
    int sum = 0;
#pragma unroll
    for (int i = 0; i < 4; ++i) {
        int idx = base + i;
        v[i] = (idx < nseg) ? cnt[idx] : 0;
        sum += v[i];
    }
    s[t] = sum;
    __syncthreads();
    int my = sum;
    for (int o = 1; o < 256; o <<= 1) {
        int x = (t >= o) ? s[t - o] : 0;
        __syncthreads();
        s[t] += x;
        __syncthreads();
    }
    int pre = s[t] - my + bsum[blockIdx.x];
#pragma unroll
    for (int i = 0; i < 4; ++i) {
        int idx = base + i;
        if (idx < nseg) {
            off[idx] = pre;
            pre += v[i];
        }
    }
}

__global__ void bucket_kernel(const int* __restrict__ src,
                              const int* __restrict__ dst,
                              const int* __restrict__ et,
                              int* __restrict__ off,
                              int* __restrict__ sids, int E, int N) {
    int e = blockIdx.x * blockDim.x + threadIdx.x;
    if (e < E) {
        int seg = et[e] * N + dst[e];
        int pos = atomicAdd(&off[seg], 1);
        sids[pos] = src[e];
    }
}

// -------- atomic-free segment mean (bf16 in/out): one wave per segment ------
__global__ __launch_bounds__(256) void aggregate_kernel(
    const ushort* __restrict__ feat,    // [N][128] bf16
    const int* __restrict__ sids,       // [E] src ids grouped by segment
    const int* __restrict__ endoff,     // [nseg] end offsets
    ushort* __restrict__ agg,           // [nseg][128] bf16 means
    int nseg) {
    int gid = blockIdx.x * blockDim.x + threadIdx.x;
    int s = gid >> 6;
    int lane = gid & 63;
    if (s >= nseg) return;
    int end = endoff[s];
    int start = (s == 0) ? 0 : endoff[s - 1];
    int deg = end - start;
    float a0 = 0.0f, a1 = 0.0f;
    for (int base = start; base < end; base += 64) {
        int m = min(64, end - base);
        int sid = (lane < m) ? sids[base + lane] : 0;
        for (int j = 0; j < m; ++j) {
            int id = __shfl(sid, j);
            unsigned v = ((const unsigned*)(feat + (size_t)id * D_IN))[lane];
            a0 += bflo(v);
            a1 += bfhi(v);
        }
    }
    float inv = (deg > 0) ? 1.0f / (float)deg : 0.0f;
    unsigned packed = (unsigned)cvbf(a0 * inv) | ((unsigned)cvbf(a1 * inv) << 16);
    ((unsigned*)(agg + (size_t)s * D_IN))[lane] = packed;
}

// ---------------- MFMA fused RGCN GEMM ----------------
// out[n][j] = bias[j] + feat[n]@root[:,j] + sum_r agg[r*N+n] @ W[r][:,j]
// 256 threads = 4 waves; wave w computes rows [bm+16w, bm+16w+16) x NCOLS.
template <int NCOLS, bool RELU, bool OUTBF16>
__global__ __launch_bounds__(256) void mfma_gemm_kernel(
    const ushort* __restrict__ feat,  // [N][128] bf16
    const ushort* __restrict__ agg,   // [R][N][128] bf16
    const ushort* __restrict__ Wt,    // [R+1][NCOLS][128] bf16 swizzled
    const float* __restrict__ bias,   // [NCOLS]
    void* __restrict__ outp,          // [N][NCOLS] bf16 or f32
    int N) {
    constexpr int NT = NCOLS / 16;  // 16x16 col-tiles per wave
    __shared__ ushort Bt[NCOLS * D_IN];

    const int tid = threadIdx.x;
    const int wave = tid >> 6;
    const int lane = tid & 63;
    const int c = lane & 15;   // A-row / D-col / B-col within tile
    const int g = lane >> 4;   // k-group
    const int rb = blockIdx.x * 64 + wave * 16;
    const int arow = min(rb + c, N - 1);

    f32x4 acc[NT];
#pragma unroll
    for (int t = 0; t < NT; ++t) acc[t] = (f32x4){0.f, 0.f, 0.f, 0.f};

    for (int s = 0; s < NREL + 1; ++s) {
        const ushort* Aseg = (s < NREL) ? (agg + (size_t)s * N * D_IN) : feat;
        // stage swizzled B segment (NCOLS x 128 bf16) linearly into LDS
        {
            const uint4* srcw = (const uint4*)(Wt + (size_t)s * NCOLS * D_IN);
            uint4* dstw = (uint4*)Bt;
#pragma unroll
            for (int i = 0; i < (NCOLS * D_IN) / (8 * 256); ++i)
                dstw[tid + i * 256] = srcw[tid + i * 256];
        }
        __syncthreads();
        const ushort* Abase = Aseg + (size_t)arow * D_IN + 8 * g;
#pragma unroll
        for (int kt = 0; kt < D_IN; kt += 32) {
            bf16x8 a = *(const bf16x8*)(Abase + kt);
#pragma unroll
            for (int t = 0; t < NT; ++t) {
                int n = t * 16 + c;
                int byteoff = n * 256 + ((kt * 2 + g * 16) ^ ((n & 7) << 4));
                bf16x8 b = *(const bf16x8*)((const char*)Bt + byteoff);
                acc[t] = __builtin_amdgcn_mfma_f32_16x16x32_bf16(a, b, acc[t], 0, 0, 0);
            }
        }
        __syncthreads();
    }

    // epilogue: D layout col=lane&15, row=(lane>>4)*4+reg
#pragma unroll
    for (int t = 0; t < NT; ++t) {
        float bv = bias[t * 16 + c];
#pragma unroll
        for (int r = 0; r < 4; ++r) {
            int orow = rb + 4 * g + r;
            if (orow < N) {
                float v = acc[t][r] + bv;
                if (RELU) v = fmaxf(v, 0.0f);
                if (OUTBF16)
                    ((ushort*)outp)[(size_t)orow * NCOLS + t * 16 + c] = cvbf(v);
                else
                    ((float*)outp)[(size_t)orow * NCOLS + t * 16 + c] = v;
            }
        }
    }
}

extern "C" void kernel_launch(void* const* d_in, const int* in_sizes, int n_in,
                              void* d_out, int out_size, void* d_ws, size_t ws_size,
                              hipStream_t stream) {
    const float* x = (const float*)d_in[0];
    const int* ei = (const int*)d_in[1];
    const int* et = (const int*)d_in[2];
    const float* W1 = (const float*)d_in[3];
    const float* root1 = (const float*)d_in[4];
    const float* bias1 = (const float*)d_in[5];
    const float* W2 = (const float*)d_in[6];
    const float* root2 = (const float*)d_in[7];
    const float* bias2 = (const float*)d_in[8];
    float* out = (float*)d_out;

    const int N = in_sizes[0] / D_IN;  // 50000
    const int E = in_sizes[2];         // 800000
    const int* src = ei;
    const int* dst = ei + E;
    const int NSEG = NREL * N;            // 400000
    const int NB = (NSEG + 1023) / 1024;  // 391 (<=512 for scan_bsum)

    // workspace layout (all 16B-aligned)
    ushort* aggb = (ushort*)d_ws;                    // NSEG*128 bf16 = 102.4 MB
    ushort* xb = aggb + (size_t)NSEG * D_IN;         // N*128 bf16    = 12.8 MB
    ushort* hb = xb + (size_t)N * D_IN;              // N*128 bf16    = 12.8 MB
    ushort* wt1 = hb + (size_t)N * D_IN;             // 9*128*128     = 0.3 MB
    ushort* wt2 = wt1 + (size_t)(NREL + 1) * D_IN * D_IN;  // 9*64*128 = 0.15 MB
    int* off = (int*)(wt2 + (size_t)(NREL + 1) * 64 * D_IN);  // NSEG ints
    int* sids = off + NSEG;                          // E ints
    int* cnt = sids + E;                             // NSEG ints
    int* bsum = cnt + NSEG;                          // NB ints

    // ---- input conversions / weight transforms (independent) ----
    to_bf16_kernel<<<(N * D_IN / 4 + 255) / 256, 256, 0, stream>>>(x, xb, N * D_IN / 4);
    wt_transform_kernel<<<((NREL + 1) * D_IN * 128 + 255) / 256, 256, 0, stream>>>(
        W1, root1, wt1, 128);
    wt_transform_kernel<<<((NREL + 1) * D_IN * 64 + 255) / 256, 256, 0, stream>>>(
        W2, root2, wt2, 64);

    // ---- CSR build (edge set identical for both layers) ----
    hipMemsetAsync(cnt, 0, (size_t)NSEG * sizeof(int), stream);
    count_kernel<<<(E + 255) / 256, 256, 0, stream>>>(dst, et, cnt, E, N);
    scan_block_sum<<<NB, 256, 0, stream>>>(cnt, bsum, NSEG);
    scan_bsum<<<1, 512, 0, stream>>>(bsum, NB);
    scan_write<<<NB, 256, 0, stream>>>(cnt, bsum, off, NSEG);
    bucket_kernel<<<(E + 255) / 256, 256, 0, stream>>>(src, dst, et, off, sids, E, N);
    // off[] now holds END offsets per segment.

    const int aggBlocks = (int)(((size_t)NSEG * 64 + 255) / 256);
    const int gemmBlocks = (N + 63) / 64;

    // ---- layer 1 ----
    aggregate_kernel<<<aggBlocks, 256, 0, stream>>>(xb, sids, off, aggb, NSEG);
    mfma_gemm_kernel<128, true, true><<<gemmBlocks, 256, 0, stream>>>(
        xb, aggb, wt1, bias1, hb, N);

    // ---- layer 2 ----
    aggregate_kernel<<<aggBlocks, 256, 0, stream>>>(hb, sids, off, aggb, NSEG);
    mfma_gemm_kernel<64, false, false><<<gemmBlocks, 256, 0, stream>>>(
        hb, aggb, wt2, bias2, out, N);
}

// Round 6
// 262.374 us; speedup vs baseline: 6.7539x; 1.4316x over previous
//
#include <hip/hip_runtime.h>
#include <hip/hip_bf16.h>

// Two-layer RGCN (mean aggregation per relation) for MI355X.
// Round 6: aggregate_kernel restructured to a 16-lane group per segment
// (mean segment degree is only 2; a 64-lane wave per segment was issue/latency
// bound at 2x its BW floor). 4 segments per wave, uint4 (16B) loads per lane.
// Everything else unchanged from round 5 (375.6 us).

#define D_IN 128
#define NREL 8

typedef short bf16x8 __attribute__((ext_vector_type(8)));
typedef float f32x4 __attribute__((ext_vector_type(4)));

__device__ __forceinline__ ushort cvbf(float f) {  // f32 -> bf16 RNE
    unsigned u = __float_as_uint(f);
    return (ushort)((u + 0x7FFFu + ((u >> 16) & 1u)) >> 16);
}
__device__ __forceinline__ float bflo(unsigned v) { return __uint_as_float(v << 16); }
__device__ __forceinline__ float bfhi(unsigned v) { return __uint_as_float(v & 0xFFFF0000u); }

// ---------------- f32 -> bf16 convert (4 elems/thread) ----------------
__global__ void to_bf16_kernel(const float* __restrict__ in,
                               ushort* __restrict__ out, int n4) {
    int i = blockIdx.x * blockDim.x + threadIdx.x;
    if (i >= n4) return;
    float4 v = ((const float4*)in)[i];
    ushort4 o;
    o.x = cvbf(v.x); o.y = cvbf(v.y); o.z = cvbf(v.z); o.w = cvbf(v.w);
    ((ushort4*)out)[i] = o;
}

// ---------------- weight pre-transform: bf16, transposed, XOR-swizzled ------
// Wt[s][n][k'] where byte-in-row = (k*2) ^ ((n&7)<<4). Segment s<NREL from W,
// s==NREL from root.
__global__ void wt_transform_kernel(const float* __restrict__ W,
                                    const float* __restrict__ root,
                                    ushort* __restrict__ Wt, int NCOLS) {
    int i = blockIdx.x * blockDim.x + threadIdx.x;
    int tot = (NREL + 1) * D_IN * NCOLS;
    if (i >= tot) return;
    int s = i / (D_IN * NCOLS);
    int r = i - s * D_IN * NCOLS;
    int k = r / NCOLS;
    int n = r - k * NCOLS;
    float v = (s < NREL) ? W[(size_t)s * D_IN * NCOLS + (size_t)k * NCOLS + n]
                         : root[(size_t)k * NCOLS + n];
    int byteoff = (k << 1) ^ ((n & 7) << 4);
    Wt[(size_t)s * NCOLS * D_IN + (size_t)n * D_IN + (byteoff >> 1)] = cvbf(v);
}

// ---------------- CSR build ----------------
__global__ void count_kernel(const int* __restrict__ dst,
                             const int* __restrict__ et,
                             int* __restrict__ cnt, int E, int N) {
    int e = blockIdx.x * blockDim.x + threadIdx.x;
    if (e < E) atomicAdd(&cnt[et[e] * N + dst[e]], 1);
}

__global__ void scan_block_sum(const int* __restrict__ cnt,
                               int* __restrict__ bsum, int nseg) {
    __shared__ int s[256];
    int base = blockIdx.x * 1024 + threadIdx.x * 4;
    int v = 0;
#pragma unroll
    for (int i = 0; i < 4; ++i) {
        int idx = base + i;
        if (idx < nseg) v += cnt[idx];
    }
    s[threadIdx.x] = v;
    __syncthreads();
    for (int off = 128; off > 0; off >>= 1) {
        if (threadIdx.x < off) s[threadIdx.x] += s[threadIdx.x + off];
        __syncthreads();
    }
    if (threadIdx.x == 0) bsum[blockIdx.x] = s[0];
}

__global__ void scan_bsum(int* __restrict__ bsum, int nb) {
    __shared__ int s[512];
    int t = threadIdx.x;
    int my = (t < nb) ? bsum[t] : 0;
    s[t] = my;
    __syncthreads();
    for (int off = 1; off < 512; off <<= 1) {
        int v = (t >= off) ? s[t - off] : 0;
        __syncthreads();
        s[t] += v;
        __syncthreads();
    }
    if (t < nb) bsum[t] = s[t] - my;  // exclusive
}

__global__ void scan_write(const int* __restrict__ cnt,
                           const int* __restrict__ bsum,
                           int* __restrict__ off, int nseg) {
    __shared__ int s[256];
    int t = threadIdx.x;
    int base = blockIdx.x * 1024 + t * 4;
    int v[4];
    int sum = 0;
#pragma unroll
    for (int i = 0; i < 4; ++i) {
        int idx = base + i;
        v[i] = (idx < nseg) ? cnt[idx] : 0;
        sum += v[i];
    }
    s[t] = sum;
    __syncthreads();
    int my = sum;
    for (int o = 1; o < 256; o <<= 1) {
        int x = (t >= o) ? s[t - o] : 0;
        __syncthreads();
        s[t] += x;
        __syncthreads();
    }
    int pre = s[t] - my + bsum[blockIdx.x];
#pragma unroll
    for (int i = 0; i < 4; ++i) {
        int idx = base + i;
        if (idx < nseg) {
            off[idx] = pre;
            pre += v[i];
        }
    }
}

__global__ void bucket_kernel(const int* __restrict__ src,
                              const int* __restrict__ dst,
                              const int* __restrict__ et,
                              int* __restrict__ off,
                              int* __restrict__ sids, int E, int N) {
    int e = blockIdx.x * blockDim.x + threadIdx.x;
    if (e < E) {
        int seg = et[e] * N + dst[e];
        int pos = atomicAdd(&off[seg], 1);
        sids[pos] = src[e];
    }
}

// -------- atomic-free segment mean (bf16 in/out): 16-lane group / segment ---
// 4 segments per wave; lane handles 16 B (8 bf16 channels) of the 256 B row.
__global__ __launch_bounds__(256) void aggregate_kernel(
    const ushort* __restrict__ feat,    // [N][128] bf16
    const int* __restrict__ sids,       // [E] src ids grouped by segment
    const int* __restrict__ endoff,     // [nseg] end offsets
    ushort* __restrict__ agg,           // [nseg][128] bf16 means
    int nseg) {
    int gid = blockIdx.x * blockDim.x + threadIdx.x;
    int s = gid >> 4;           // one segment per 16 threads
    int l = gid & 15;           // lane within group
    if (s >= nseg) return;
    int gbase = threadIdx.x & 48;  // group's base lane within the wave

    int end = endoff[s];
    int start = (s == 0) ? 0 : endoff[s - 1];
    int deg = end - start;

    float acc[8] = {0.f, 0.f, 0.f, 0.f, 0.f, 0.f, 0.f, 0.f};
    for (int base = start; base < end; base += 16) {
        int m = min(16, end - base);
        int sid = (l < m) ? sids[base + l] : 0;
#pragma unroll 2
        for (int j = 0; j < m; ++j) {
            int id = __shfl(sid, gbase + j);
            uint4 v = ((const uint4*)(feat + (size_t)id * D_IN))[l];
            acc[0] += bflo(v.x); acc[1] += bfhi(v.x);
            acc[2] += bflo(v.y); acc[3] += bfhi(v.y);
            acc[4] += bflo(v.z); acc[5] += bfhi(v.z);
            acc[6] += bflo(v.w); acc[7] += bfhi(v.w);
        }
    }
    float inv = (deg > 0) ? 1.0f / (float)deg : 0.0f;
    uint4 o;
    o.x = (unsigned)cvbf(acc[0] * inv) | ((unsigned)cvbf(acc[1] * inv) << 16);
    o.y = (unsigned)cvbf(acc[2] * inv) | ((unsigned)cvbf(acc[3] * inv) << 16);
    o.z = (unsigned)cvbf(acc[4] * inv) | ((unsigned)cvbf(acc[5] * inv) << 16);
    o.w = (unsigned)cvbf(acc[6] * inv) | ((unsigned)cvbf(acc[7] * inv) << 16);
    ((uint4*)(agg + (size_t)s * D_IN))[l] = o;
}

// ---------------- MFMA fused RGCN GEMM ----------------
// out[n][j] = bias[j] + feat[n]@root[:,j] + sum_r agg[r*N+n] @ W[r][:,j]
// 256 threads = 4 waves; wave w computes rows [bm+16w, bm+16w+16) x NCOLS.
template <int NCOLS, bool RELU, bool OUTBF16>
__global__ __launch_bounds__(256) void mfma_gemm_kernel(
    const ushort* __restrict__ feat,  // [N][128] bf16
    const ushort* __restrict__ agg,   // [R][N][128] bf16
    const ushort* __restrict__ Wt,    // [R+1][NCOLS][128] bf16 swizzled
    const float* __restrict__ bias,   // [NCOLS]
    void* __restrict__ outp,          // [N][NCOLS] bf16 or f32
    int N) {
    constexpr int NT = NCOLS / 16;  // 16x16 col-tiles per wave
    __shared__ ushort Bt[NCOLS * D_IN];

    const int tid = threadIdx.x;
    const int wave = tid >> 6;
    const int lane = tid & 63;
    const int c = lane & 15;   // A-row / D-col / B-col within tile
    const int g = lane >> 4;   // k-group
    const int rb = blockIdx.x * 64 + wave * 16;
    const int arow = min(rb + c, N - 1);

    f32x4 acc[NT];
#pragma unroll
    for (int t = 0; t < NT; ++t) acc[t] = (f32x4){0.f, 0.f, 0.f, 0.f};

    for (int s = 0; s < NREL + 1; ++s) {
        const ushort* Aseg = (s < NREL) ? (agg + (size_t)s * N * D_IN) : feat;
        // stage swizzled B segment (NCOLS x 128 bf16) linearly into LDS
        {
            const uint4* srcw = (const uint4*)(Wt + (size_t)s * NCOLS * D_IN);
            uint4* dstw = (uint4*)Bt;
#pragma unroll
            for (int i = 0; i < (NCOLS * D_IN) / (8 * 256); ++i)
                dstw[tid + i * 256] = srcw[tid + i * 256];
        }
        __syncthreads();
        const ushort* Abase = Aseg + (size_t)arow * D_IN + 8 * g;
#pragma unroll
        for (int kt = 0; kt < D_IN; kt += 32) {
            bf16x8 a = *(const bf16x8*)(Abase + kt);
#pragma unroll
            for (int t = 0; t < NT; ++t) {
                int n = t * 16 + c;
                int byteoff = n * 256 + ((kt * 2 + g * 16) ^ ((n & 7) << 4));
                bf16x8 b = *(const bf16x8*)((const char*)Bt + byteoff);
                acc[t] = __builtin_amdgcn_mfma_f32_16x16x32_bf16(a, b, acc[t], 0, 0, 0);
            }
        }
        __syncthreads();
    }

    // epilogue: D layout col=lane&15, row=(lane>>4)*4+reg
#pragma unroll
    for (int t = 0; t < NT; ++t) {
        float bv = bias[t * 16 + c];
#pragma unroll
        for (int r = 0; r < 4; ++r) {
            int orow = rb + 4 * g + r;
            if (orow < N) {
                float v = acc[t][r] + bv;
                if (RELU) v = fmaxf(v, 0.0f);
                if (OUTBF16)
                    ((ushort*)outp)[(size_t)orow * NCOLS + t * 16 + c] = cvbf(v);
                else
                    ((float*)outp)[(size_t)orow * NCOLS + t * 16 + c] = v;
            }
        }
    }
}

extern "C" void kernel_launch(void* const* d_in, const int* in_sizes, int n_in,
                              void* d_out, int out_size, void* d_ws, size_t ws_size,
                              hipStream_t stream) {
    const float* x = (const float*)d_in[0];
    const int* ei = (const int*)d_in[1];
    const int* et = (const int*)d_in[2];
    const float* W1 = (const float*)d_in[3];
    const float* root1 = (const float*)d_in[4];
    const float* bias1 = (const float*)d_in[5];
    const float* W2 = (const float*)d_in[6];
    const float* root2 = (const float*)d_in[7];
    const float* bias2 = (const float*)d_in[8];
    float* out = (float*)d_out;

    const int N = in_sizes[0] / D_IN;  // 50000
    const int E = in_sizes[2];         // 800000
    const int* src = ei;
    const int* dst = ei + E;
    const int NSEG = NREL * N;            // 400000
    const int NB = (NSEG + 1023) / 1024;  // 391 (<=512 for scan_bsum)

    // workspace layout (all 16B-aligned)
    ushort* aggb = (ushort*)d_ws;                    // NSEG*128 bf16 = 102.4 MB
    ushort* xb = aggb + (size_t)NSEG * D_IN;         // N*128 bf16    = 12.8 MB
    ushort* hb = xb + (size_t)N * D_IN;              // N*128 bf16    = 12.8 MB
    ushort* wt1 = hb + (size_t)N * D_IN;             // 9*128*128     = 0.3 MB
    ushort* wt2 = wt1 + (size_t)(NREL + 1) * D_IN * D_IN;  // 9*64*128 = 0.15 MB
    int* off = (int*)(wt2 + (size_t)(NREL + 1) * 64 * D_IN);  // NSEG ints
    int* sids = off + NSEG;                          // E ints
    int* cnt = sids + E;                             // NSEG ints
    int* bsum = cnt + NSEG;                          // NB ints

    // ---- input conversions / weight transforms (independent) ----
    to_bf16_kernel<<<(N * D_IN / 4 + 255) / 256, 256, 0, stream>>>(x, xb, N * D_IN / 4);
    wt_transform_kernel<<<((NREL + 1) * D_IN * 128 + 255) / 256, 256, 0, stream>>>(
        W1, root1, wt1, 128);
    wt_transform_kernel<<<((NREL + 1) * D_IN * 64 + 255) / 256, 256, 0, stream>>>(
        W2, root2, wt2, 64);

    // ---- CSR build (edge set identical for both layers) ----
    hipMemsetAsync(cnt, 0, (size_t)NSEG * sizeof(int), stream);
    count_kernel<<<(E + 255) / 256, 256, 0, stream>>>(dst, et, cnt, E, N);
    scan_block_sum<<<NB, 256, 0, stream>>>(cnt, bsum, NSEG);
    scan_bsum<<<1, 512, 0, stream>>>(bsum, NB);
    scan_write<<<NB, 256, 0, stream>>>(cnt, bsum, off, NSEG);
    bucket_kernel<<<(E + 255) / 256, 256, 0, stream>>>(src, dst, et, off, sids, E, N);
    // off[] now holds END offsets per segment.

    const int aggBlocks = (int)(((size_t)NSEG * 16 + 255) / 256);
    const int gemmBlocks = (N + 63) / 64;

    // ---- layer 1 ----
    aggregate_kernel<<<aggBlocks, 256, 0, stream>>>(xb, sids, off, aggb, NSEG);
    mfma_gemm_kernel<128, true, true><<<gemmBlocks, 256, 0, stream>>>(
        xb, aggb, wt1, bias1, hb, N);

    // ---- layer 2 ----
    aggregate_kernel<<<aggBlocks, 256, 0, stream>>>(hb, sids, off, aggb, NSEG);
    mfma_gemm_kernel<64, false, false><<<gemmBlocks, 256, 0, stream>>>(
        hb, aggb, wt2, bias2, out, N);
}

// Round 7
// 258.830 us; speedup vs baseline: 6.8463x; 1.0137x over previous
//
#include <hip/hip_runtime.h>
#include <hip/hip_bf16.h>

// Two-layer RGCN (mean aggregation per relation) for MI355X.
// Round 7: FUSE aggregation into the MFMA GEMM. The agg buffer (102 MB write +
// ~96 MB fetch-on-write + 102 MB read-back per layer) is eliminated; each MFMA
// lane builds its A-fragment by gathering its (relation,dst) segment's rows
// (mean deg = 2) from the LLC-resident feature matrix and averaging in
// registers. CSR build + converts unchanged from round 6 (262.4 us).

#define D_IN 128
#define NREL 8

typedef short bf16x8 __attribute__((ext_vector_type(8)));
typedef float f32x4 __attribute__((ext_vector_type(4)));

__device__ __forceinline__ ushort cvbf(float f) {  // f32 -> bf16 RNE
    unsigned u = __float_as_uint(f);
    return (ushort)((u + 0x7FFFu + ((u >> 16) & 1u)) >> 16);
}
__device__ __forceinline__ float bflo(unsigned v) { return __uint_as_float(v << 16); }
__device__ __forceinline__ float bfhi(unsigned v) { return __uint_as_float(v & 0xFFFF0000u); }

// ---------------- f32 -> bf16 convert (4 elems/thread) ----------------
__global__ void to_bf16_kernel(const float* __restrict__ in,
                               ushort* __restrict__ out, int n4) {
    int i = blockIdx.x * blockDim.x + threadIdx.x;
    if (i >= n4) return;
    float4 v = ((const float4*)in)[i];
    ushort4 o;
    o.x = cvbf(v.x); o.y = cvbf(v.y); o.z = cvbf(v.z); o.w = cvbf(v.w);
    ((ushort4*)out)[i] = o;
}

// ---------------- weight pre-transform: bf16, transposed, XOR-swizzled ------
// Wt[s][n][k'] where byte-in-row = (k*2) ^ ((n&7)<<4). Segment s<NREL from W,
// s==NREL from root.
__global__ void wt_transform_kernel(const float* __restrict__ W,
                                    const float* __restrict__ root,
                                    ushort* __restrict__ Wt, int NCOLS) {
    int i = blockIdx.x * blockDim.x + threadIdx.x;
    int tot = (NREL + 1) * D_IN * NCOLS;
    if (i >= tot) return;
    int s = i / (D_IN * NCOLS);
    int r = i - s * D_IN * NCOLS;
    int k = r / NCOLS;
    int n = r - k * NCOLS;
    float v = (s < NREL) ? W[(size_t)s * D_IN * NCOLS + (size_t)k * NCOLS + n]
                         : root[(size_t)k * NCOLS + n];
    int byteoff = (k << 1) ^ ((n & 7) << 4);
    Wt[(size_t)s * NCOLS * D_IN + (size_t)n * D_IN + (byteoff >> 1)] = cvbf(v);
}

// ---------------- CSR build ----------------
__global__ void count_kernel(const int* __restrict__ dst,
                             const int* __restrict__ et,
                             int* __restrict__ cnt, int E, int N) {
    int e = blockIdx.x * blockDim.x + threadIdx.x;
    if (e < E) atomicAdd(&cnt[et[e] * N + dst[e]], 1);
}

__global__ void scan_block_sum(const int* __restrict__ cnt,
                               int* __restrict__ bsum, int nseg) {
    __shared__ int s[256];
    int base = blockIdx.x * 1024 + threadIdx.x * 4;
    int v = 0;
#pragma unroll
    for (int i = 0; i < 4; ++i) {
        int idx = base + i;
        if (idx < nseg) v += cnt[idx];
    }
    s[threadIdx.x] = v;
    __syncthreads();
    for (int off = 128; off > 0; off >>= 1) {
        if (threadIdx.x < off) s[threadIdx.x] += s[threadIdx.x + off];
        __syncthreads();
    }
    if (threadIdx.x == 0) bsum[blockIdx.x] = s[0];
}

__global__ void scan_bsum(int* __restrict__ bsum, int nb) {
    __shared__ int s[512];
    int t = threadIdx.x;
    int my = (t < nb) ? bsum[t] : 0;
    s[t] = my;
    __syncthreads();
    for (int off = 1; off < 512; off <<= 1) {
        int v = (t >= off) ? s[t - off] : 0;
        __syncthreads();
        s[t] += v;
        __syncthreads();
    }
    if (t < nb) bsum[t] = s[t] - my;  // exclusive
}

__global__ void scan_write(const int* __restrict__ cnt,
                           const int* __restrict__ bsum,
                           int* __restrict__ off, int nseg) {
    __shared__ int s[256];
    int t = threadIdx.x;
    int base = blockIdx.x * 1024 + t * 4;
    int v[4];
    int sum = 0;
#pragma unroll
    for (int i = 0; i < 4; ++i) {
        int idx = base + i;
        v[i] = (idx < nseg) ? cnt[idx] : 0;
        sum += v[i];
    }
    s[t] = sum;
    __syncthreads();
    int my = sum;
    for (int o = 1; o < 256; o <<= 1) {
        int x = (t >= o) ? s[t - o] : 0;
        __syncthreads();
        s[t] += x;
        __syncthreads();
    }
    int pre = s[t] - my + bsum[blockIdx.x];
#pragma unroll
    for (int i = 0; i < 4; ++i) {
        int idx = base + i;
        if (idx < nseg) {
            off[idx] = pre;
            pre += v[i];
        }
    }
}

__global__ void bucket_kernel(const int* __restrict__ src,
                              const int* __restrict__ dst,
                              const int* __restrict__ et,
                              int* __restrict__ off,
                              int* __restrict__ sids, int E, int N) {
    int e = blockIdx.x * blockDim.x + threadIdx.x;
    if (e < E) {
        int seg = et[e] * N + dst[e];
        int pos = atomicAdd(&off[seg], 1);
        sids[pos] = src[e];
    }
}

// ---------------- fused aggregate + MFMA GEMM ----------------
// out[n][j] = bias[j] + feat[n]@root[:,j]
//           + sum_r mean_{e in seg(r,n)} feat[src_e] @ W[r][:,j]
// 256 threads = 4 waves; wave w computes rows [rb, rb+16) x NCOLS.
// Lane (c,g) gathers+averages its row's segment on the fly (A-fragment),
// channels kt*32 + 8g + 0..7 for kt=0..3.
template <int NCOLS, bool RELU, bool OUTBF16>
__global__ __launch_bounds__(256) void fused_gemm_kernel(
    const ushort* __restrict__ feat,   // [N][128] bf16
    const int* __restrict__ sids,      // [E] src ids grouped by (rel,dst) seg
    const int* __restrict__ endoff,    // [R*N] end offsets
    const ushort* __restrict__ Wt,     // [R+1][NCOLS][128] bf16 swizzled
    const float* __restrict__ bias,    // [NCOLS]
    void* __restrict__ outp,           // [N][NCOLS] bf16 or f32
    int N) {
    constexpr int NT = NCOLS / 16;  // 16x16 col-tiles per wave
    __shared__ ushort Bt[NCOLS * D_IN];

    const int tid = threadIdx.x;
    const int wave = tid >> 6;
    const int lane = tid & 63;
    const int c = lane & 15;   // A-row / D-col / B-col within tile
    const int g = lane >> 4;   // k-group
    const int rb = blockIdx.x * 64 + wave * 16;
    const int arow = min(rb + c, N - 1);  // clamped; stores are guarded

    f32x4 acc[NT];
#pragma unroll
    for (int t = 0; t < NT; ++t) acc[t] = (f32x4){0.f, 0.f, 0.f, 0.f};

    for (int s = 0; s < NREL + 1; ++s) {
        // stage swizzled B segment (NCOLS x 128 bf16) linearly into LDS
        {
            const uint4* srcw = (const uint4*)(Wt + (size_t)s * NCOLS * D_IN);
            uint4* dstw = (uint4*)Bt;
#pragma unroll
            for (int i = 0; i < (NCOLS * D_IN) / (8 * 256); ++i)
                dstw[tid + i * 256] = srcw[tid + i * 256];
        }
        __syncthreads();

        // build A fragments afr[q] = channels q*32 + 8g + 0..7 of this row's
        // segment mean (s < NREL) or of feat[arow] itself (root segment).
        bf16x8 afr[4];
        if (s < NREL) {
            int seg = s * N + arow;
            int end = endoff[seg];
            int start = (seg == 0) ? 0 : endoff[seg - 1];
            int deg = end - start;
            float ac[4][8];
#pragma unroll
            for (int q = 0; q < 4; ++q)
#pragma unroll
                for (int j = 0; j < 8; ++j) ac[q][j] = 0.0f;
            for (int e = start; e < end; ++e) {
                int id = sids[e];
                const ushort* row = feat + (size_t)id * D_IN + 8 * g;
#pragma unroll
                for (int q = 0; q < 4; ++q) {
                    uint4 v = *(const uint4*)(row + 32 * q);
                    ac[q][0] += bflo(v.x); ac[q][1] += bfhi(v.x);
                    ac[q][2] += bflo(v.y); ac[q][3] += bfhi(v.y);
                    ac[q][4] += bflo(v.z); ac[q][5] += bfhi(v.z);
                    ac[q][6] += bflo(v.w); ac[q][7] += bfhi(v.w);
                }
            }
            float inv = (deg > 0) ? 1.0f / (float)deg : 0.0f;
#pragma unroll
            for (int q = 0; q < 4; ++q) {
                unsigned w0 = (unsigned)cvbf(ac[q][0] * inv) | ((unsigned)cvbf(ac[q][1] * inv) << 16);
                unsigned w1 = (unsigned)cvbf(ac[q][2] * inv) | ((unsigned)cvbf(ac[q][3] * inv) << 16);
                unsigned w2 = (unsigned)cvbf(ac[q][4] * inv) | ((unsigned)cvbf(ac[q][5] * inv) << 16);
                unsigned w3 = (unsigned)cvbf(ac[q][6] * inv) | ((unsigned)cvbf(ac[q][7] * inv) << 16);
                uint4 packed = make_uint4(w0, w1, w2, w3);
                afr[q] = *(bf16x8*)&packed;
            }
        } else {
            const ushort* row = feat + (size_t)arow * D_IN + 8 * g;
#pragma unroll
            for (int q = 0; q < 4; ++q) afr[q] = *(const bf16x8*)(row + 32 * q);
        }

#pragma unroll
        for (int q = 0; q < 4; ++q) {
            const int kt = q * 32;
#pragma unroll
            for (int t = 0; t < NT; ++t) {
                int n = t * 16 + c;
                int byteoff = n * 256 + ((kt * 2 + g * 16) ^ ((n & 7) << 4));
                bf16x8 b = *(const bf16x8*)((const char*)Bt + byteoff);
                acc[t] = __builtin_amdgcn_mfma_f32_16x16x32_bf16(afr[q], b, acc[t], 0, 0, 0);
            }
        }
        __syncthreads();
    }

    // epilogue: D layout col=lane&15, row=(lane>>4)*4+reg
#pragma unroll
    for (int t = 0; t < NT; ++t) {
        float bv = bias[t * 16 + c];
#pragma unroll
        for (int r = 0; r < 4; ++r) {
            int orow = rb + 4 * g + r;
            if (orow < N) {
                float v = acc[t][r] + bv;
                if (RELU) v = fmaxf(v, 0.0f);
                if (OUTBF16)
                    ((ushort*)outp)[(size_t)orow * NCOLS + t * 16 + c] = cvbf(v);
                else
                    ((float*)outp)[(size_t)orow * NCOLS + t * 16 + c] = v;
            }
        }
    }
}

extern "C" void kernel_launch(void* const* d_in, const int* in_sizes, int n_in,
                              void* d_out, int out_size, void* d_ws, size_t ws_size,
                              hipStream_t stream) {
    const float* x = (const float*)d_in[0];
    const int* ei = (const int*)d_in[1];
    const int* et = (const int*)d_in[2];
    const float* W1 = (const float*)d_in[3];
    const float* root1 = (const float*)d_in[4];
    const float* bias1 = (const float*)d_in[5];
    const float* W2 = (const float*)d_in[6];
    const float* root2 = (const float*)d_in[7];
    const float* bias2 = (const float*)d_in[8];
    float* out = (float*)d_out;

    const int N = in_sizes[0] / D_IN;  // 50000
    const int E = in_sizes[2];         // 800000
    const int* src = ei;
    const int* dst = ei + E;
    const int NSEG = NREL * N;            // 400000
    const int NB = (NSEG + 1023) / 1024;  // 391 (<=512 for scan_bsum)

    // workspace layout (all 16B-aligned)
    ushort* xb = (ushort*)d_ws;                      // N*128 bf16 = 12.8 MB
    ushort* hb = xb + (size_t)N * D_IN;              // N*128 bf16 = 12.8 MB
    ushort* wt1 = hb + (size_t)N * D_IN;             // 9*128*128  = 0.3 MB
    ushort* wt2 = wt1 + (size_t)(NREL + 1) * D_IN * D_IN;  // 9*64*128
    int* off = (int*)(wt2 + (size_t)(NREL + 1) * 64 * D_IN);  // NSEG ints
    int* sids = off + NSEG;                          // E ints
    int* cnt = sids + E;                             // NSEG ints
    int* bsum = cnt + NSEG;                          // NB ints

    // ---- input conversions / weight transforms (independent) ----
    to_bf16_kernel<<<(N * D_IN / 4 + 255) / 256, 256, 0, stream>>>(x, xb, N * D_IN / 4);
    wt_transform_kernel<<<((NREL + 1) * D_IN * 128 + 255) / 256, 256, 0, stream>>>(
        W1, root1, wt1, 128);
    wt_transform_kernel<<<((NREL + 1) * D_IN * 64 + 255) / 256, 256, 0, stream>>>(
        W2, root2, wt2, 64);

    // ---- CSR build (edge set identical for both layers) ----
    hipMemsetAsync(cnt, 0, (size_t)NSEG * sizeof(int), stream);
    count_kernel<<<(E + 255) / 256, 256, 0, stream>>>(dst, et, cnt, E, N);
    scan_block_sum<<<NB, 256, 0, stream>>>(cnt, bsum, NSEG);
    scan_bsum<<<1, 512, 0, stream>>>(bsum, NB);
    scan_write<<<NB, 256, 0, stream>>>(cnt, bsum, off, NSEG);
    bucket_kernel<<<(E + 255) / 256, 256, 0, stream>>>(src, dst, et, off, sids, E, N);
    // off[] now holds END offsets per segment.

    const int gemmBlocks = (N + 63) / 64;

    // ---- layer 1 (fused aggregate+GEMM) ----
    fused_gemm_kernel<128, true, true><<<gemmBlocks, 256, 0, stream>>>(
        xb, sids, off, wt1, bias1, hb, N);

    // ---- layer 2 ----
    fused_gemm_kernel<64, false, false><<<gemmBlocks, 256, 0, stream>>>(
        hb, sids, off, wt2, bias2, out, N);
}